// Round 2
// baseline (753.882 us; speedup 1.0000x reference)
//
#include <hip/hip_runtime.h>

// MoE top-2, B=8 T=4096 D=512 H=1536 E=8.
// R7: T3/T4-min pipeline on both GEMMs. ffn1 was 148us at MfmaUtil 30% /
// VALU 35% / HBM 12% -- the single-buffer 2-barrier profile (stage, drain,
// compute serialized per K-step). Now: LDS double-buffer, issue next tile's
// 8 global_load_lds BEFORE computing current, raw s_barrier (NOT
// __syncthreads -- compiler would emit vmcnt(0) and drain the prefetch),
// counted s_waitcnt vmcnt(8) so prefetch stays in flight across the barrier.
// LDS 32.5->64.5KB, 2 blocks/CU. Same indexing/swizzle as R6.

#define N_TOK 32768
#define DIM   512
#define HID   1536
#define NE    8
#define MTS   256   // max 128-row tiles per expert (worst case ne=32768)

typedef __attribute__((ext_vector_type(8))) short  short8;
typedef __attribute__((ext_vector_type(4))) float  floatx4;

#define MFMA(a,b,c) __builtin_amdgcn_mfma_f32_16x16x32_bf16(a,b,c,0,0,0)

__device__ __forceinline__ unsigned short f2bf(float f) {
  unsigned int u = __float_as_uint(f);
  u += 0x7fffu + ((u >> 16) & 1u);
  return (unsigned short)(u >> 16);
}
__device__ __forceinline__ unsigned pk2(float a, float b) {
  return (unsigned)f2bf(a) | ((unsigned)f2bf(b) << 16);
}
// async global->LDS, 16B per lane; dst = wave-uniform base + lane*16
__device__ __forceinline__ void gl_lds16(const unsigned short* g, unsigned short* l) {
  __builtin_amdgcn_global_load_lds(
      (const __attribute__((address_space(1))) unsigned int*)g,
      (__attribute__((address_space(3))) unsigned int*)l, 16, 0, 0);
}

// ---------------- fp32 -> bf16 weight conversion ----------------
__global__ void __launch_bounds__(256) cvt_kernel(const float* __restrict__ src,
                                                  unsigned short* __restrict__ dst,
                                                  int n4) {
  int i = blockIdx.x * 256 + threadIdx.x;
  if (i >= n4) return;
  float4 v = ((const float4*)src)[i];
  uint2 o; o.x = pk2(v.x, v.y); o.y = pk2(v.z, v.w);
  ((uint2*)dst)[i] = o;
}

// ------------- gate phase 1: logits (fp64), top-2, softmax; also x->bf16 -------------
__global__ void __launch_bounds__(256) gate1_kernel(const float* __restrict__ x,
                                                    const float* __restrict__ gw,
                                                    unsigned short* __restrict__ xb,
                                                    unsigned* __restrict__ eidx,
                                                    float* __restrict__ wts) {
  int lane = threadIdx.x & 63;
  int wave = threadIdx.x >> 6;
  int t = blockIdx.x * 4 + wave;

  const float4* xp = (const float4*)(x + (size_t)t * DIM + lane * 8);
  float4 x0 = xp[0], x1 = xp[1];

  uint4 o; o.x = pk2(x0.x, x0.y); o.y = pk2(x0.z, x0.w);
  o.z = pk2(x1.x, x1.y); o.w = pk2(x1.z, x1.w);
  *(uint4*)(xb + (size_t)t * DIM + lane * 8) = o;

  double p[NE];
#pragma unroll
  for (int e = 0; e < NE; ++e) {
    const float4* gp = (const float4*)(gw + e * DIM + lane * 8);
    float4 g0 = gp[0], g1 = gp[1];
    p[e] = (double)x0.x * g0.x + (double)x0.y * g0.y + (double)x0.z * g0.z + (double)x0.w * g0.w
         + (double)x1.x * g1.x + (double)x1.y * g1.y + (double)x1.z * g1.z + (double)x1.w * g1.w;
  }
#pragma unroll
  for (int m = 1; m < 64; m <<= 1) {
#pragma unroll
    for (int e = 0; e < NE; ++e) p[e] += __shfl_xor(p[e], m);
  }
  if (lane == 0) {
    double m1 = -1e300, m2 = -1e300; int i1 = 0, i2 = 0;
#pragma unroll
    for (int e = 0; e < NE; ++e) {
      double v = p[e];
      if (v > m1) { m2 = m1; i2 = i1; m1 = v; i1 = e; }
      else if (v > m2) { m2 = v; i2 = e; }
    }
    float e2 = __expf((float)(m2 - m1));
    float wa = 1.f / (1.f + e2);
    eidx[t] = (unsigned)i1 | ((unsigned)i2 << 8);
    wts[t]  = wa;
  }
}

// ---------------- gate phase 2: per-expert lists (LDS hist + range reserve) ----------
// tokl entry: token | (k<<31)   (k=0 primary, k=1 secondary)
__global__ void __launch_bounds__(256) gate2_kernel(const unsigned* __restrict__ eidx,
                                                    const float* __restrict__ wts,
                                                    int* __restrict__ tokl,
                                                    float* __restrict__ wgtl,
                                                    int* __restrict__ cnt) {
  __shared__ unsigned hist[NE];
  __shared__ unsigned basep[NE];
  int tid = threadIdx.x;
  if (tid < NE) hist[tid] = 0;
  __syncthreads();
  int t0 = blockIdx.x * 1024;
  unsigned pk[4]; float wv[4];
#pragma unroll
  for (int i = 0; i < 4; ++i) {
    int t = t0 + tid + i * 256;
    pk[i] = eidx[t]; wv[i] = wts[t];
    atomicAdd(&hist[pk[i] & 0xff], 1u);
    atomicAdd(&hist[(pk[i] >> 8) & 0xff], 1u);
  }
  __syncthreads();
  if (tid < NE) {
    basep[tid] = (unsigned)atomicAdd(&cnt[tid], (int)hist[tid]);
    hist[tid] = 0;
  }
  __syncthreads();
#pragma unroll
  for (int i = 0; i < 4; ++i) {
    int t = t0 + tid + i * 256;
    int e1 = pk[i] & 0xff, e2 = (pk[i] >> 8) & 0xff;
    unsigned p1 = basep[e1] + atomicAdd(&hist[e1], 1u);
    tokl[e1 * N_TOK + p1] = t; wgtl[e1 * N_TOK + p1] = wv[i];
    unsigned p2 = basep[e2] + atomicAdd(&hist[e2], 1u);
    tokl[e2 * N_TOK + p2] = t | (int)0x80000000; wgtl[e2 * N_TOK + p2] = 1.f - wv[i];
  }
}

// ---------------- GEMM1: Hs = wgt * silu(X w1^T) * (X w3^T), bf16 ----------------
// tile: 128 tokens x 64 h-cols. Bs = [w1 rows 0..63 | w3 rows 0..63].
// wave (wm,wn): tokens wm*64.., h-cols wn*32..; u/v accs match lanes -> reg silu.
// Double-buffered K-loop, counted vmcnt, raw barriers.
__global__ void __launch_bounds__(256, 2) ffn1_kernel(
    const unsigned short* __restrict__ xb,
    const unsigned short* __restrict__ w1b,
    const unsigned short* __restrict__ w3b,
    const int* __restrict__ tokl, const float* __restrict__ wgtl,
    const int* __restrict__ cnt,
    unsigned short* __restrict__ Hs,
    int h0base, int P, int NT) {
  int e  = blockIdx.x & 7;
  int t  = blockIdx.x >> 3;
  int nt = t % NT, mt = t / NT;
  int ne = cnt[e];
  int m0 = mt * 128;
  if (m0 >= ne) return;
  int offs = 0;
#pragma unroll
  for (int i = 0; i < NE; ++i) offs += (i < e) ? cnt[i] : 0;

  __shared__ __align__(16) unsigned short As[2][128 * 64];   // XOR-swizzled chunks
  __shared__ __align__(16) unsigned short Bs[2][128 * 64];
  __shared__ float wgs[128];

  int tid = threadIdx.x, w = tid >> 6, lane = tid & 63;
  int quad = lane >> 4, l16 = lane & 15;
  int wm = w >> 1, wn = w & 1;

  if (tid < 128) {
    int r = m0 + tid;
    wgs[tid] = (r < ne) ? wgtl[e * N_TOK + r] : 0.f;
  }

  int rl = lane >> 3, cc = (lane & 7) ^ rl;   // staging: XOR-swizzled source chunk
  const unsigned short* pa[4];
#pragma unroll
  for (int i = 0; i < 4; ++i) {
    int r = m0 + 32 * w + 8 * i + rl;
    int tok = tokl[e * N_TOK + (r < ne ? r : m0)] & 0x7fffffff;
    pa[i] = xb + (size_t)tok * DIM + cc * 8;
  }
  // B rows regular: one base pointer, const strides
  const unsigned short* wsrc = (w < 2) ? w1b : w3b;
  const unsigned short* pb0 =
      wsrc + ((size_t)e * HID + h0base + nt * 64 + ((32 * w) & 63) + rl) * DIM + cc * 8;

  // stage one 64-K tile into buffer b; advances pointers by 64 K
  auto stage = [&](int b) {
#pragma unroll
    for (int i = 0; i < 4; ++i) {
      gl_lds16(pa[i], &As[b][(32 * w + 8 * i) * 64]);
      gl_lds16(pb0 + (size_t)i * 8 * DIM, &Bs[b][(32 * w + 8 * i) * 64]);
      pa[i] += 64;
    }
    pb0 += 64;
  };

  floatx4 u[4][2], v[4][2];
#pragma unroll
  for (int i = 0; i < 4; ++i)
#pragma unroll
    for (int j = 0; j < 2; ++j) { u[i][j] = (floatx4){0,0,0,0}; v[i][j] = (floatx4){0,0,0,0}; }

  stage(0);
  int cur = 0;
#pragma unroll
  for (int k0 = 0; k0 < DIM; k0 += 64) {
    if (k0 + 64 < DIM) {
      stage(cur ^ 1);                                   // next tile in flight
      asm volatile("s_waitcnt vmcnt(8)" ::: "memory");  // cur tile landed; 8 newer stay
    } else {
      asm volatile("s_waitcnt vmcnt(0)" ::: "memory");
    }
    __builtin_amdgcn_s_barrier();
#pragma unroll
    for (int kk = 0; kk < 2; ++kk) {
      int s = ((4 * kk + quad) ^ (l16 & 7)) * 8;   // all row bases ≡ 0 mod 8
      short8 a[4], b1[2], b3[2];
#pragma unroll
      for (int i = 0; i < 4; ++i)
        a[i] = *(const short8*)&As[cur][(wm * 64 + i * 16 + l16) * 64 + s];
#pragma unroll
      for (int j = 0; j < 2; ++j) {
        b1[j] = *(const short8*)&Bs[cur][(wn * 32 + j * 16 + l16) * 64 + s];
        b3[j] = *(const short8*)&Bs[cur][(64 + wn * 32 + j * 16 + l16) * 64 + s];
      }
#pragma unroll
      for (int i = 0; i < 4; ++i)
#pragma unroll
        for (int j = 0; j < 2; ++j) {
          u[i][j] = MFMA(a[i], b1[j], u[i][j]);
          v[i][j] = MFMA(a[i], b3[j], v[i][j]);
        }
    }
    asm volatile("" ::: "memory");
    __builtin_amdgcn_s_barrier();   // all reads of buf[cur] done before overwrite
    cur ^= 1;
  }

  // ---- epilogue: in-register silu, pack to LDS (reuse As[0]), coalesced store ----
#pragma unroll
  for (int i = 0; i < 4; ++i)
#pragma unroll
    for (int j = 0; j < 2; ++j)
#pragma unroll
      for (int r = 0; r < 4; ++r) {
        int tr = wm * 64 + i * 16 + quad * 4 + r;
        int hc = wn * 32 + j * 16 + l16;
        float uu = u[i][j][r], vv = v[i][j][r];
        float h = (uu / (1.f + __expf(-uu))) * vv * wgs[tr];
        As[0][tr * 64 + hc] = f2bf(h);
      }
  __syncthreads();
  {
    int row = tid >> 1, half = tid & 1;
    if (m0 + row < ne) {
      const unsigned short* s = &As[0][row * 64 + half * 32];
      unsigned short* d = Hs + (size_t)(offs + m0 + row) * P + nt * 64 + half * 32;
#pragma unroll
      for (int j = 0; j < 4; ++j) *(uint4*)(d + j * 8) = *(const uint4*)(s + j * 8);
    }
  }
}

// ---------------- GEMM2: out/prt = Hs @ w2^T (gate weight already folded) ----------
// tile: M=128 tokens x N=128 d-cols, BK=64, K=P. Double-buffered, counted vmcnt.
// No atomics: primary rows (tokl bit31==0) target out[], secondary target prt[].
// first pass stores, later passes do regular load+add+store RMW.
__global__ void __launch_bounds__(256, 2) ffn2_kernel(
    const unsigned short* __restrict__ Hs,
    const unsigned short* __restrict__ w2b,
    const int* __restrict__ tokl, const int* __restrict__ cnt,
    float* __restrict__ out, float* __restrict__ prt,
    int h0base, int P, int first) {
  int e  = blockIdx.x & 7;
  int t  = blockIdx.x >> 3;
  int nt = t & 3, mt = t >> 2;
  int ne = cnt[e];
  int m0 = mt * 128;
  if (m0 >= ne) return;
  int offs = 0;
#pragma unroll
  for (int i = 0; i < NE; ++i) offs += (i < e) ? cnt[i] : 0;

  __shared__ __align__(16) unsigned short As[2][128 * 64];
  __shared__ __align__(16) unsigned short Bs[2][128 * 64];
  __shared__ int toks[128];

  int tid = threadIdx.x, w = tid >> 6, lane = tid & 63;
  int quad = lane >> 4, l16 = lane & 15;
  int wm = w >> 1, wn = w & 1;
  if (tid < 128) { int r = m0 + tid; toks[tid] = tokl[e * N_TOK + (r < ne ? r : m0)]; }

  int rl = lane >> 3, cc = (lane & 7) ^ rl;
  int dbase = nt * 128;
  // both A (Hs rows, slot-ordered) and B (w2 rows) are regular: base + const strides
  const unsigned short* pa0 = Hs + (size_t)(offs + m0 + 32 * w + rl) * P + cc * 8;
  const unsigned short* pb0 =
      w2b + ((size_t)e * DIM + dbase + 32 * w + rl) * HID + h0base + cc * 8;

  auto stage = [&](int b) {
#pragma unroll
    for (int i = 0; i < 4; ++i) {
      gl_lds16(pa0 + (size_t)i * 8 * P,   &As[b][(32 * w + 8 * i) * 64]);
      gl_lds16(pb0 + (size_t)i * 8 * HID, &Bs[b][(32 * w + 8 * i) * 64]);
    }
    pa0 += 64; pb0 += 64;
  };

  floatx4 acc[4][4];
#pragma unroll
  for (int i = 0; i < 4; ++i)
#pragma unroll
    for (int j = 0; j < 4; ++j) acc[i][j] = (floatx4){0,0,0,0};

  stage(0);
  int cur = 0;
  for (int k0 = 0; k0 < P; k0 += 64) {
    if (k0 + 64 < P) {
      stage(cur ^ 1);
      asm volatile("s_waitcnt vmcnt(8)" ::: "memory");
    } else {
      asm volatile("s_waitcnt vmcnt(0)" ::: "memory");
    }
    __builtin_amdgcn_s_barrier();
#pragma unroll
    for (int kk = 0; kk < 2; ++kk) {
      int s = ((4 * kk + quad) ^ (l16 & 7)) * 8;
      short8 a[4], b[4];
#pragma unroll
      for (int i = 0; i < 4; ++i) {
        a[i] = *(const short8*)&As[cur][(wm * 64 + i * 16 + l16) * 64 + s];
        b[i] = *(const short8*)&Bs[cur][(wn * 64 + i * 16 + l16) * 64 + s];
      }
#pragma unroll
      for (int i = 0; i < 4; ++i)
#pragma unroll
        for (int j = 0; j < 4; ++j)
          acc[i][j] = MFMA(a[i], b[j], acc[i][j]);
    }
    asm volatile("" ::: "memory");
    __builtin_amdgcn_s_barrier();
    cur ^= 1;
  }

#pragma unroll
  for (int i = 0; i < 4; ++i)
#pragma unroll
    for (int r = 0; r < 4; ++r) {
      int row = wm * 64 + i * 16 + quad * 4 + r;
      if (m0 + row >= ne) continue;
      int tk = toks[row];
      float* dst = ((tk < 0) ? prt : out)
                   + (size_t)(tk & 0x7fffffff) * DIM + dbase + wn * 64 + l16;
      if (first) {
#pragma unroll
        for (int j = 0; j < 4; ++j) dst[j * 16] = acc[i][j][r];
      } else {
#pragma unroll
        for (int j = 0; j < 4; ++j) dst[j * 16] += acc[i][j][r];
      }
    }
}

// ---------------- combine: out += prt (primary + secondary halves) ----------------
__global__ void __launch_bounds__(256) combine_kernel(float* __restrict__ out,
                                                      const float* __restrict__ prt,
                                                      int n4) {
  for (int i = blockIdx.x * 256 + threadIdx.x; i < n4; i += gridDim.x * 256) {
    float4 a = ((const float4*)out)[i];
    float4 b = ((const float4*)prt)[i];
    a.x += b.x; a.y += b.y; a.z += b.z; a.w += b.w;
    ((float4*)out)[i] = a;
  }
}

extern "C" void kernel_launch(void* const* d_in, const int* in_sizes, int n_in,
                              void* d_out, int out_size, void* d_ws, size_t ws_size,
                              hipStream_t stream) {
  const float* x  = (const float*)d_in[0];
  const float* gw = (const float*)d_in[1];
  const float* w1 = (const float*)d_in[2];
  const float* w3 = (const float*)d_in[3];
  const float* w2 = (const float*)d_in[4];
  float* out = (float*)d_out;

  const size_t NW = (size_t)NE * HID * DIM;
  char* p = (char*)d_ws;
  unsigned short* w1b = (unsigned short*)p;  p += NW * 2;
  unsigned short* w3b = (unsigned short*)p;  p += NW * 2;
  unsigned short* w2b = (unsigned short*)p;  p += NW * 2;
  unsigned short* xb  = (unsigned short*)p;  p += (size_t)N_TOK * DIM * 2;
  int*      tokl = (int*)p;       p += (size_t)NE * N_TOK * 4;
  float*    wgtl = (float*)p;     p += (size_t)NE * N_TOK * 4;
  unsigned* eidx = (unsigned*)p;  p += (size_t)N_TOK * 4;
  float*    wts  = (float*)p;     p += (size_t)N_TOK * 4;
  int*      cnt  = (int*)p;       p += 256;
  float*    prt  = (float*)p;     p += (size_t)N_TOK * DIM * 4;   // secondary-slot partials
  unsigned short* Hs = (unsigned short*)p;
  size_t fixed = (size_t)(p - (char*)d_ws);
  if (ws_size < fixed) return;
  size_t avail = ws_size - fixed;

  const int cands[5] = {1536, 768, 512, 384, 256};
  int P = 0;
  for (int i = 0; i < 5; ++i)
    if ((size_t)(2 * N_TOK + 128) * cands[i] * 2 <= avail) { P = cands[i]; break; }
  if (!P) return;

  hipMemsetAsync(cnt, 0, NE * sizeof(int), stream);

  int n4 = (int)(NW / 4);
  cvt_kernel<<<n4 / 256, 256, 0, stream>>>(w1, w1b, n4);
  cvt_kernel<<<n4 / 256, 256, 0, stream>>>(w3, w3b, n4);
  cvt_kernel<<<n4 / 256, 256, 0, stream>>>(w2, w2b, n4);

  gate1_kernel<<<N_TOK / 4, 256, 0, stream>>>(x, gw, xb, eidx, wts);
  gate2_kernel<<<N_TOK / 1024, 256, 0, stream>>>(eidx, wts, tokl, wgtl, cnt);

  int pass = 0;
  for (int h0 = 0; h0 < HID; h0 += P) {
    int NT = P / 64;
    ffn1_kernel<<<8 * MTS * NT, 256, 0, stream>>>(xb, w1b, w3b, tokl, wgtl, cnt, Hs, h0, P, NT);
    ffn2_kernel<<<8 * MTS * 4, 256, 0, stream>>>(Hs, w2b, tokl, cnt, out, prt, h0, P, pass == 0);
    ++pass;
  }
  combine_kernel<<<2048, 256, 0, stream>>>(out, prt, N_TOK * DIM / 4);
}

// Round 3
// 686.549 us; speedup vs baseline: 1.0981x; 1.0981x over previous
//
#include <hip/hip_runtime.h>

// MoE top-2, B=8 T=4096 D=512 H=1536 E=8.
// R8: ffn1 -> 256-tile 8-phase-class schedule (T3+T4+T5). R7 showed 2-deep
// dbuf at 128x64 tiles loses more TLP than it gains (occ 40->21%, Mfma
// 30->25%). Per guide regime-gate, counted-vmcnt pipelining pays only with
// the big-tile phase-split structure: BM=256 tok, B=256 rows (128 w1 || 128
// w3 -> every wave owns matching u/v quadrants, in-register silu kept),
// BK=64, 8 waves, LDS 128KB dbuf, 1 block/CU. Per K-tile 4 phases:
// {stage 1 half-tile of t+1; vmcnt(4/4/-/-); s_barrier; ds_read quadrant;
// lgkmcnt(0)+sched_barrier; setprio(1); 16 MFMA; setprio(0); s_barrier}.
// Last tile peeled with vmcnt(2/0). ffn2 reverted to known-good R6 form.

#define N_TOK 32768
#define DIM   512
#define HID   1536
#define NE    8
#define MTS   256   // max 128-row tiles per expert (ffn2)
#define MT1   128   // max 256-row tiles per expert (ffn1)

typedef __attribute__((ext_vector_type(8))) short  short8;
typedef __attribute__((ext_vector_type(4))) float  floatx4;

#define MFMA(a,b,c) __builtin_amdgcn_mfma_f32_16x16x32_bf16(a,b,c,0,0,0)

#define VMW4 asm volatile("s_waitcnt vmcnt(4)" ::: "memory")
#define VMW2 asm volatile("s_waitcnt vmcnt(2)" ::: "memory")
#define VMW0 asm volatile("s_waitcnt vmcnt(0)" ::: "memory")
#define LG0  do { asm volatile("s_waitcnt lgkmcnt(0)" ::: "memory"); \
                  __builtin_amdgcn_sched_barrier(0); } while (0)
#define BARR __builtin_amdgcn_s_barrier()

__device__ __forceinline__ unsigned short f2bf(float f) {
  unsigned int u = __float_as_uint(f);
  u += 0x7fffu + ((u >> 16) & 1u);
  return (unsigned short)(u >> 16);
}
__device__ __forceinline__ unsigned pk2(float a, float b) {
  return (unsigned)f2bf(a) | ((unsigned)f2bf(b) << 16);
}
// async global->LDS, 16B per lane; dst = wave-uniform base + lane*16
__device__ __forceinline__ void gl_lds16(const unsigned short* g, unsigned short* l) {
  __builtin_amdgcn_global_load_lds(
      (const __attribute__((address_space(1))) unsigned int*)g,
      (__attribute__((address_space(3))) unsigned int*)l, 16, 0, 0);
}

// ---------------- fp32 -> bf16 weight conversion ----------------
__global__ void __launch_bounds__(256) cvt_kernel(const float* __restrict__ src,
                                                  unsigned short* __restrict__ dst,
                                                  int n4) {
  int i = blockIdx.x * 256 + threadIdx.x;
  if (i >= n4) return;
  float4 v = ((const float4*)src)[i];
  uint2 o; o.x = pk2(v.x, v.y); o.y = pk2(v.z, v.w);
  ((uint2*)dst)[i] = o;
}

// ------------- gate phase 1: logits (fp64), top-2, softmax; also x->bf16 -------------
__global__ void __launch_bounds__(256) gate1_kernel(const float* __restrict__ x,
                                                    const float* __restrict__ gw,
                                                    unsigned short* __restrict__ xb,
                                                    unsigned* __restrict__ eidx,
                                                    float* __restrict__ wts) {
  int lane = threadIdx.x & 63;
  int wave = threadIdx.x >> 6;
  int t = blockIdx.x * 4 + wave;

  const float4* xp = (const float4*)(x + (size_t)t * DIM + lane * 8);
  float4 x0 = xp[0], x1 = xp[1];

  uint4 o; o.x = pk2(x0.x, x0.y); o.y = pk2(x0.z, x0.w);
  o.z = pk2(x1.x, x1.y); o.w = pk2(x1.z, x1.w);
  *(uint4*)(xb + (size_t)t * DIM + lane * 8) = o;

  double p[NE];
#pragma unroll
  for (int e = 0; e < NE; ++e) {
    const float4* gp = (const float4*)(gw + e * DIM + lane * 8);
    float4 g0 = gp[0], g1 = gp[1];
    p[e] = (double)x0.x * g0.x + (double)x0.y * g0.y + (double)x0.z * g0.z + (double)x0.w * g0.w
         + (double)x1.x * g1.x + (double)x1.y * g1.y + (double)x1.z * g1.z + (double)x1.w * g1.w;
  }
#pragma unroll
  for (int m = 1; m < 64; m <<= 1) {
#pragma unroll
    for (int e = 0; e < NE; ++e) p[e] += __shfl_xor(p[e], m);
  }
  if (lane == 0) {
    double m1 = -1e300, m2 = -1e300; int i1 = 0, i2 = 0;
#pragma unroll
    for (int e = 0; e < NE; ++e) {
      double v = p[e];
      if (v > m1) { m2 = m1; i2 = i1; m1 = v; i1 = e; }
      else if (v > m2) { m2 = v; i2 = e; }
    }
    float e2 = __expf((float)(m2 - m1));
    float wa = 1.f / (1.f + e2);
    eidx[t] = (unsigned)i1 | ((unsigned)i2 << 8);
    wts[t]  = wa;
  }
}

// ---------------- gate phase 2: per-expert lists (LDS hist + range reserve) ----------
// tokl entry: token | (k<<31)   (k=0 primary, k=1 secondary)
__global__ void __launch_bounds__(256) gate2_kernel(const unsigned* __restrict__ eidx,
                                                    const float* __restrict__ wts,
                                                    int* __restrict__ tokl,
                                                    float* __restrict__ wgtl,
                                                    int* __restrict__ cnt) {
  __shared__ unsigned hist[NE];
  __shared__ unsigned basep[NE];
  int tid = threadIdx.x;
  if (tid < NE) hist[tid] = 0;
  __syncthreads();
  int t0 = blockIdx.x * 1024;
  unsigned pk[4]; float wv[4];
#pragma unroll
  for (int i = 0; i < 4; ++i) {
    int t = t0 + tid + i * 256;
    pk[i] = eidx[t]; wv[i] = wts[t];
    atomicAdd(&hist[pk[i] & 0xff], 1u);
    atomicAdd(&hist[(pk[i] >> 8) & 0xff], 1u);
  }
  __syncthreads();
  if (tid < NE) {
    basep[tid] = (unsigned)atomicAdd(&cnt[tid], (int)hist[tid]);
    hist[tid] = 0;
  }
  __syncthreads();
#pragma unroll
  for (int i = 0; i < 4; ++i) {
    int t = t0 + tid + i * 256;
    int e1 = pk[i] & 0xff, e2 = (pk[i] >> 8) & 0xff;
    unsigned p1 = basep[e1] + atomicAdd(&hist[e1], 1u);
    tokl[e1 * N_TOK + p1] = t; wgtl[e1 * N_TOK + p1] = wv[i];
    unsigned p2 = basep[e2] + atomicAdd(&hist[e2], 1u);
    tokl[e2 * N_TOK + p2] = t | (int)0x80000000; wgtl[e2 * N_TOK + p2] = 1.f - wv[i];
  }
}

// ---------------- GEMM1 (8-phase): Hs = wgt * silu(X w1^T) * (X w3^T) ----------------
// BM=256 tokens, B rows = [w1 h-cols 0..127 | w3 h-cols 0..127], BK=64, K=512.
// 8 waves 2M x 4N; wave owns 128 tok x (32 u-cols + 32 v-cols) -> reg silu.
// LDS: A,B double-buffered 32KB each buf = 128KB total.
__global__ void __launch_bounds__(512, 2) ffn1_kernel(
    const unsigned short* __restrict__ xb,
    const unsigned short* __restrict__ w1b,
    const unsigned short* __restrict__ w3b,
    const int* __restrict__ tokl, const float* __restrict__ wgtl,
    const int* __restrict__ cnt,
    unsigned short* __restrict__ Hs,
    int h0base, int P, int NT) {
  int e  = blockIdx.x & 7;
  int t  = blockIdx.x >> 3;
  int nt = t % NT, mt = t / NT;
  int ne = cnt[e];
  int m0 = mt * 256;
  if (m0 >= ne) return;
  int offs = 0;
#pragma unroll
  for (int i = 0; i < NE; ++i) offs += (i < e) ? cnt[i] : 0;

  __shared__ __align__(16) unsigned short sA[2][256 * 64];
  __shared__ __align__(16) unsigned short sB[2][256 * 64];
  __shared__ float wgs[256];

  int tid = threadIdx.x, w = tid >> 6, lane = tid & 63;
  int quad = lane >> 4, l16 = lane & 15;
  int wm = w >> 2, wn = w & 3;
  int rl = lane >> 3, c8 = lane & 7;
  int sw = (c8 ^ rl) * 8;   // pre-swizzled source chunk (inverse of read XOR)

  if (tid < 256) {
    int r = m0 + tid;
    wgs[tid] = (r < ne) ? wgtl[e * N_TOK + r] : 0.f;
  }

  // A gather pointers: (half h, load ld) -> row h*128 + ld*64 + w*8 + rl
  const unsigned short* pa[2][2];
#pragma unroll
  for (int h = 0; h < 2; ++h)
#pragma unroll
    for (int ld = 0; ld < 2; ++ld) {
      int row = h * 128 + ld * 64 + w * 8 + rl;
      int rr = m0 + row;
      int tok = tokl[e * N_TOK + (rr < ne ? rr : m0)] & 0x7fffffff;
      pa[h][ld] = xb + (size_t)tok * DIM + sw;
    }
  // B pointers: half 0 = w1, half 1 = w3 (same h-col rows)
  const unsigned short* pb[2][2];
#pragma unroll
  for (int h = 0; h < 2; ++h)
#pragma unroll
    for (int ld = 0; ld < 2; ++ld) {
      const unsigned short* ws = h ? w3b : w1b;
      int hr = h0base + nt * 128 + ld * 64 + w * 8 + rl;
      pb[h][ld] = ws + ((size_t)e * HID + hr) * DIM + sw;
    }

  auto stA = [&](int buf, int h, int kadd) {
    unsigned short* d = &sA[buf][(h * 128 + w * 8) * 64];
    gl_lds16(pa[h][0] + kadd, d);
    gl_lds16(pa[h][1] + kadd, d + 64 * 64);
  };
  auto stB = [&](int buf, int h, int kadd) {
    unsigned short* d = &sB[buf][(h * 128 + w * 8) * 64];
    gl_lds16(pb[h][0] + kadd, d);
    gl_lds16(pb[h][1] + kadd, d + 64 * 64);
  };

  short8 a[4][2], bu[2][2], bv[2][2];
  floatx4 au[2][4][2], av[2][4][2];
#pragma unroll
  for (int mi = 0; mi < 2; ++mi)
#pragma unroll
    for (int i = 0; i < 4; ++i)
#pragma unroll
      for (int j = 0; j < 2; ++j) {
        au[mi][i][j] = (floatx4){0, 0, 0, 0};
        av[mi][i][j] = (floatx4){0, 0, 0, 0};
      }

  auto ldA = [&](int buf, int mi) {
#pragma unroll
    for (int i = 0; i < 4; ++i)
#pragma unroll
      for (int kk = 0; kk < 2; ++kk)
        a[i][kk] = *(const short8*)&sA[buf][(wm * 128 + mi * 64 + i * 16 + l16) * 64 +
                                           (((4 * kk + quad) ^ (l16 & 7)) * 8)];
  };
  auto ldB = [&](int buf, int h, short8 (&b)[2][2]) {
#pragma unroll
    for (int j = 0; j < 2; ++j)
#pragma unroll
      for (int kk = 0; kk < 2; ++kk)
        b[j][kk] = *(const short8*)&sB[buf][(h * 128 + wn * 32 + j * 16 + l16) * 64 +
                                           (((4 * kk + quad) ^ (l16 & 7)) * 8)];
  };
  auto mm = [&](short8 (&b)[2][2], floatx4 (&ac)[4][2]) {
    __builtin_amdgcn_s_setprio(1);
#pragma unroll
    for (int i = 0; i < 4; ++i)
#pragma unroll
      for (int j = 0; j < 2; ++j)
#pragma unroll
        for (int kk = 0; kk < 2; ++kk)
          ac[i][j] = MFMA(a[i][kk], b[j][kk], ac[i][j]);
    __builtin_amdgcn_s_setprio(0);
  };

  // prologue: tile 0, issue order == steady-state order (A0, A1, B0, B1)
  stA(0, 0, 0); stA(0, 1, 0); stB(0, 0, 0); stB(0, 1, 0);

  int cur = 0;
  for (int tt = 0; tt < (DIM / 64) - 1; ++tt) {   // 7 main K-tiles
    int kadd = (tt + 1) * 64;
    int nx = cur ^ 1;
    // ph0: needs A(t) both halves + B-h0(t)
    stA(nx, 0, kadd);
    VMW4; BARR;
    ldA(cur, 0); ldB(cur, 0, bu);
    LG0; mm(bu, au[0]); BARR;
    // ph1: needs B-h1(t)
    stA(nx, 1, kadd);
    VMW4; BARR;
    ldB(cur, 1, bv);
    LG0; mm(bv, av[0]); BARR;
    // ph2: A mi=1 (already certified)
    stB(nx, 0, kadd);
    BARR;
    ldA(cur, 1);
    LG0; mm(bu, au[1]); BARR;
    // ph3: regs only
    stB(nx, 1, kadd);
    BARR;
    mm(bv, av[1]); BARR;
    cur = nx;
  }
  // last tile (no stages in flight behind it -> tight waits)
  VMW2; BARR;
  ldA(cur, 0); ldB(cur, 0, bu);
  LG0; mm(bu, au[0]); BARR;
  VMW0; BARR;
  ldB(cur, 1, bv);
  LG0; mm(bv, av[0]); BARR;
  BARR;
  ldA(cur, 1);
  LG0; mm(bu, au[1]); BARR;
  mm(bv, av[1]);
  __syncthreads();

  // ---- epilogue: in-register silu, pack to LDS (reuse sA: 256 x 128 bf16) ----
  unsigned short* AsF = &sA[0][0];
#pragma unroll
  for (int mi = 0; mi < 2; ++mi)
#pragma unroll
    for (int i = 0; i < 4; ++i)
#pragma unroll
      for (int j = 0; j < 2; ++j)
#pragma unroll
        for (int r = 0; r < 4; ++r) {
          int tr = wm * 128 + mi * 64 + i * 16 + quad * 4 + r;
          int hc = wn * 32 + j * 16 + l16;
          float uu = au[mi][i][j][r], vv = av[mi][i][j][r];
          float h = (uu / (1.f + __expf(-uu))) * vv * wgs[tr];
          AsF[tr * 128 + hc] = f2bf(h);
        }
  __syncthreads();
  {
#pragma unroll
    for (int ro = 0; ro < 8; ++ro) {
      int row = ro * 32 + (tid >> 4);
      int ch = (tid & 15) * 8;
      if (m0 + row < ne) {
        *(uint4*)(Hs + (size_t)(offs + m0 + row) * P + nt * 128 + ch) =
            *(const uint4*)(AsF + row * 128 + ch);
      }
    }
  }
}

// ---------------- GEMM2: out/prt = Hs @ w2^T (gate weight already folded) ----------
// tile: M=128 tokens x N=128 d-cols, BK=64, K=P. (R6 known-good form.)
// No atomics: primary rows (tokl bit31==0) target out[], secondary target prt[].
// first pass stores, later passes do regular load+add+store RMW.
__global__ void __launch_bounds__(256, 4) ffn2_kernel(
    const unsigned short* __restrict__ Hs,
    const unsigned short* __restrict__ w2b,
    const int* __restrict__ tokl, const int* __restrict__ cnt,
    float* __restrict__ out, float* __restrict__ prt,
    int h0base, int P, int first) {
  int e  = blockIdx.x & 7;
  int t  = blockIdx.x >> 3;
  int nt = t & 3, mt = t >> 2;
  int ne = cnt[e];
  int m0 = mt * 128;
  if (m0 >= ne) return;
  int offs = 0;
#pragma unroll
  for (int i = 0; i < NE; ++i) offs += (i < e) ? cnt[i] : 0;

  __shared__ __align__(16) unsigned short As[128 * 64];
  __shared__ __align__(16) unsigned short Bs[128 * 64];
  __shared__ int toks[128];

  int tid = threadIdx.x, w = tid >> 6, lane = tid & 63;
  int quad = lane >> 4, l16 = lane & 15;
  int wm = w >> 1, wn = w & 1;
  if (tid < 128) { int r = m0 + tid; toks[tid] = tokl[e * N_TOK + (r < ne ? r : m0)]; }

  int rl = lane >> 3, cc = (lane & 7) ^ rl;
  int dbase = nt * 128;
  const unsigned short* pa0 = Hs + (size_t)(offs + m0 + 32 * w + rl) * P + cc * 8;
  const unsigned short* pb0 =
      w2b + ((size_t)e * DIM + dbase + 32 * w + rl) * HID + h0base + cc * 8;

  floatx4 acc[4][4];
#pragma unroll
  for (int i = 0; i < 4; ++i)
#pragma unroll
    for (int j = 0; j < 4; ++j) acc[i][j] = (floatx4){0, 0, 0, 0};

  for (int k0 = 0; k0 < P; k0 += 64) {
#pragma unroll
    for (int i = 0; i < 4; ++i) {
      gl_lds16(pa0 + (size_t)i * 8 * P,   &As[(32 * w + 8 * i) * 64]);
      gl_lds16(pb0 + (size_t)i * 8 * HID, &Bs[(32 * w + 8 * i) * 64]);
    }
    pa0 += 64; pb0 += 64;
    __syncthreads();
#pragma unroll
    for (int kk = 0; kk < 2; ++kk) {
      int s = ((4 * kk + quad) ^ (l16 & 7)) * 8;
      short8 a[4], b[4];
#pragma unroll
      for (int i = 0; i < 4; ++i) {
        a[i] = *(const short8*)&As[(wm * 64 + i * 16 + l16) * 64 + s];
        b[i] = *(const short8*)&Bs[(wn * 64 + i * 16 + l16) * 64 + s];
      }
#pragma unroll
      for (int i = 0; i < 4; ++i)
#pragma unroll
        for (int j = 0; j < 4; ++j)
          acc[i][j] = MFMA(a[i], b[j], acc[i][j]);
    }
    __syncthreads();
  }

#pragma unroll
  for (int i = 0; i < 4; ++i)
#pragma unroll
    for (int r = 0; r < 4; ++r) {
      int row = wm * 64 + i * 16 + quad * 4 + r;
      if (m0 + row >= ne) continue;
      int tk = toks[row];
      float* dst = ((tk < 0) ? prt : out)
                   + (size_t)(tk & 0x7fffffff) * DIM + dbase + wn * 64 + l16;
      if (first) {
#pragma unroll
        for (int j = 0; j < 4; ++j) dst[j * 16] = acc[i][j][r];
      } else {
#pragma unroll
        for (int j = 0; j < 4; ++j) dst[j * 16] += acc[i][j][r];
      }
    }
}

// ---------------- combine: out += prt (primary + secondary halves) ----------------
__global__ void __launch_bounds__(256) combine_kernel(float* __restrict__ out,
                                                      const float* __restrict__ prt,
                                                      int n4) {
  for (int i = blockIdx.x * 256 + threadIdx.x; i < n4; i += gridDim.x * 256) {
    float4 a = ((const float4*)out)[i];
    float4 b = ((const float4*)prt)[i];
    a.x += b.x; a.y += b.y; a.z += b.z; a.w += b.w;
    ((float4*)out)[i] = a;
  }
}

extern "C" void kernel_launch(void* const* d_in, const int* in_sizes, int n_in,
                              void* d_out, int out_size, void* d_ws, size_t ws_size,
                              hipStream_t stream) {
  const float* x  = (const float*)d_in[0];
  const float* gw = (const float*)d_in[1];
  const float* w1 = (const float*)d_in[2];
  const float* w3 = (const float*)d_in[3];
  const float* w2 = (const float*)d_in[4];
  float* out = (float*)d_out;

  const size_t NW = (size_t)NE * HID * DIM;
  char* p = (char*)d_ws;
  unsigned short* w1b = (unsigned short*)p;  p += NW * 2;
  unsigned short* w3b = (unsigned short*)p;  p += NW * 2;
  unsigned short* w2b = (unsigned short*)p;  p += NW * 2;
  unsigned short* xb  = (unsigned short*)p;  p += (size_t)N_TOK * DIM * 2;
  int*      tokl = (int*)p;       p += (size_t)NE * N_TOK * 4;
  float*    wgtl = (float*)p;     p += (size_t)NE * N_TOK * 4;
  unsigned* eidx = (unsigned*)p;  p += (size_t)N_TOK * 4;
  float*    wts  = (float*)p;     p += (size_t)N_TOK * 4;
  int*      cnt  = (int*)p;       p += 256;
  float*    prt  = (float*)p;     p += (size_t)N_TOK * DIM * 4;   // secondary-slot partials
  unsigned short* Hs = (unsigned short*)p;
  size_t fixed = (size_t)(p - (char*)d_ws);
  if (ws_size < fixed) return;
  size_t avail = ws_size - fixed;

  const int cands[5] = {1536, 768, 512, 384, 256};
  int P = 0;
  for (int i = 0; i < 5; ++i)
    if ((size_t)(2 * N_TOK + 128) * cands[i] * 2 <= avail) { P = cands[i]; break; }
  if (!P) return;

  hipMemsetAsync(cnt, 0, NE * sizeof(int), stream);

  int n4 = (int)(NW / 4);
  cvt_kernel<<<n4 / 256, 256, 0, stream>>>(w1, w1b, n4);
  cvt_kernel<<<n4 / 256, 256, 0, stream>>>(w3, w3b, n4);
  cvt_kernel<<<n4 / 256, 256, 0, stream>>>(w2, w2b, n4);

  gate1_kernel<<<N_TOK / 4, 256, 0, stream>>>(x, gw, xb, eidx, wts);
  gate2_kernel<<<N_TOK / 1024, 256, 0, stream>>>(eidx, wts, tokl, wgtl, cnt);

  int pass = 0;
  for (int h0 = 0; h0 < HID; h0 += P) {
    int NT1 = P / 128;
    ffn1_kernel<<<8 * MT1 * NT1, 512, 0, stream>>>(xb, w1b, w3b, tokl, wgtl, cnt, Hs, h0, P, NT1);
    ffn2_kernel<<<8 * MTS * 4, 256, 0, stream>>>(Hs, w2b, tokl, cnt, out, prt, h0, P, pass == 0);
    ++pass;
  }
  combine_kernel<<<2048, 256, 0, stream>>>(out, prt, N_TOK * DIM / 4);
}